// Round 13
// baseline (964.737 us; speedup 1.0000x reference)
//
#include <hip/hip_runtime.h>

typedef __attribute__((ext_vector_type(8))) short bf16x8;
typedef __attribute__((ext_vector_type(4))) float f32x4;
typedef __attribute__((ext_vector_type(4))) float f4v;

#define NU 150000
#define NI 50000
#define NTOT 200000
// stream GEMM K: user [id64|wv300]=364 -> 384; item [id64|wv300|snt768]=1132 -> 1152
#define KSU 364
#define KSUP 384
#define KSI 1132
#define KSIP 1152

__device__ __forceinline__ f4v ld4(const float* p) { return *(const f4v*)p; }

__device__ __forceinline__ unsigned short bf16r(float x) {
    unsigned u = __float_as_uint(x);
    u += 0x7fff + ((u >> 16) & 1);
    return (unsigned short)(u >> 16);
}
__device__ __forceinline__ unsigned pk2(float lo, float hi) {
    unsigned a = __float_as_uint(lo), b = __float_as_uint(hi);
    a += 0x7fff + ((a >> 16) & 1);
    b += 0x7fff + ((b >> 16) & 1);
    return (a >> 16) | (b & 0xffff0000u);
}
__device__ __forceinline__ float bfu(unsigned short u) {
    return __uint_as_float((unsigned)u << 16);
}

// W [K][64] fp32 -> WT [64][Kpad] bf16 (zero-padded)
__global__ void prep_wt(const float* __restrict__ src, unsigned short* __restrict__ dst,
                        int K, int Kpad) {
    const int c = blockIdx.y;
    const int k = blockIdx.x * 256 + threadIdx.x;
    if (k >= Kpad) return;
    dst[(size_t)c * Kpad + k] = (k < K) ? bf16r(src[(size_t)k * 64 + c]) : (unsigned short)0;
}

// Stream-slice W: k' < 64 -> k', else k'+160 (skips feat[64,128)+text[128,224) rows)
__global__ void prep_wt_remap(const float* __restrict__ src, unsigned short* __restrict__ dst,
                              int K, int Kpad) {
    const int c = blockIdx.y;
    const int kp = blockIdx.x * 256 + threadIdx.x;
    if (kp >= Kpad) return;
    unsigned short v = 0;
    if (kp < K) {
        const int k = kp + (kp >= 64 ? 160 : 0);
        v = bf16r(src[(size_t)k * 64 + c]);
    }
    dst[(size_t)c * Kpad + kp] = v;
}

// ---------------------------------------------------------------------------
// Projected table: dst[r][c] = bf16( scale * sum_k tab[r][k] * W[koff+k][c] )
// wave per row: lane c, tab row loads are wave-uniform (scalar), W L1-hot.
// ---------------------------------------------------------------------------
__global__ __launch_bounds__(256, 8) void proj_tab(
    const float* __restrict__ tab, const float* __restrict__ W,
    int koff, int K, float scale, unsigned short* __restrict__ dst, int R)
{
    const int row = blockIdx.x * 4 + (threadIdx.x >> 6);
    const int c = threadIdx.x & 63;
    if (row >= R) return;
    const float* tr = tab + (size_t)row * K;
    float s = 0.f;
    for (int k = 0; k < K; ++k)
        s += tr[k] * W[(size_t)(koff + k) * 64 + c];
    dst[(size_t)row * 64 + c] = bf16r(s * scale);
}

// ---------------------------------------------------------------------------
// Gather-sum of projected tables: per node sum 29 rows (5 feat + 24 word,
// scales pre-folded) + projb + numb + numeric@numW -> x_partial bf16.
// Wave per node; lane=(c,h): one instr covers 2 full 128B rows. Indices
// preloaded (uniform), 15 paired gathers fully unrolled -> deep MLP.
// ---------------------------------------------------------------------------
__global__ __launch_bounds__(256, 8) void gather_psum(
    const unsigned short* __restrict__ Pfu, const unsigned short* __restrict__ Pfi,
    const unsigned short* __restrict__ Pw_u, const unsigned short* __restrict__ Pw_i,
    const int* __restrict__ ufi, const int* __restrict__ ifi,
    const int* __restrict__ uti, const int* __restrict__ iti,
    const float* __restrict__ unum, const float* __restrict__ inum,
    const float* __restrict__ unw, const float* __restrict__ inw,
    const float* __restrict__ upb, const float* __restrict__ ipb,
    const float* __restrict__ unb, const float* __restrict__ inb,
    unsigned short* __restrict__ xp)
{
    __shared__ __align__(16) unsigned short st[4][64];
    const int t = threadIdx.x;
    const int wid = t >> 6, lane = t & 63;
    const int node = blockIdx.x * 4 + wid;
    const int c = lane & 31, h = lane >> 5;
    const bool isu = node < NU;
    const int ln = isu ? node : node - NU;

    const int* fip = (isu ? ufi : ifi) + (size_t)ln * 5;
    const int* tip = (isu ? uti : iti) + (size_t)ln * 24;
    const unsigned short* Pf = isu ? Pfu : Pfi;
    const unsigned short* Pw = isu ? Pw_u : Pw_i;   // 3 fields contiguous, 30000*64 apart

    int fid[5], tid[24];
    #pragma unroll
    for (int j = 0; j < 5; ++j) fid[j] = fip[j];
    #pragma unroll
    for (int j = 0; j < 24; ++j) tid[j] = tip[j];

    float s0 = 0.f, s1 = 0.f;
    #pragma unroll
    for (int i = 0; i < 15; ++i) {
        const int ri = 2 * i + h;
        if (ri < 29) {
            const unsigned short* p;
            if (ri < 5) p = Pf + (size_t)fid[ri] * 64;
            else {
                const int q = ri - 5;
                p = Pw + (size_t)(q >> 3) * (30000 * 64) + (size_t)tid[q] * 64;
            }
            const unsigned d = *(const unsigned*)(p + 2 * c);
            s0 += bfu((unsigned short)(d & 0xffff));
            s1 += bfu((unsigned short)(d >> 16));
        }
    }
    s0 += __shfl_xor(s0, 32, 64);
    s1 += __shfl_xor(s1, 32, 64);

    // epilogue: biases + numeric side-GEMM
    const float* nw = isu ? unw : inw;
    const float* pb = isu ? upb : ipb;
    const float* nb = isu ? unb : inb;
    const float* nm = (isu ? unum : inum) + (size_t)ln * 10;
    const int c0 = 2 * c, c1 = 2 * c + 1;
    float e0 = pb[c0] + nb[c0], e1 = pb[c1] + nb[c1];
    #pragma unroll
    for (int j = 0; j < 10; ++j) {
        const float nv = nm[j];
        e0 += nv * nw[j * 64 + c0];
        e1 += nv * nw[j * 64 + c1];
    }
    s0 += e0; s1 += e1;

    if (h == 0) *(unsigned*)&st[wid][2 * c] = pk2(s0, s1);
    __syncthreads();
    if (t < 32) {   // 4 nodes x 128B contiguous
        const uint4 v = *(const uint4*)&st[0][t * 8];
        *(uint4*)(xp + (size_t)blockIdx.x * 256 + t * 8) = v;
    }
}

// ---------------------------------------------------------------------------
// Pure-stream GEMM: x0 = [id | wordvec | (sentence)] @ WT' + x_partial.
// R10 2-barrier pipeline, contiguous staging lane-map, NO gathers/branch-div.
// ---------------------------------------------------------------------------
__global__ __launch_bounds__(256, 6) void stream_gemm(
    const float* __restrict__ id_emb, const float* __restrict__ wordvec,
    const float* __restrict__ sentence, const unsigned short* __restrict__ WT,
    const unsigned short* __restrict__ xp,
    unsigned short* __restrict__ x_out, int n, int Ks, int Kpad, int row_off)
{
    __shared__ __align__(16) unsigned short aS[64][72];
    const int t = threadIdx.x;
    const int row0 = blockIdx.x * 64;

    const int ch  = (t & 15) * 4;
    const int rsub = t >> 4;

    const int lane = t & 63;
    const int w16 = (t >> 6) * 16;
    const int l15 = lane & 15;
    const int hi8 = (lane >> 4) * 8;
    const int g4  = (lane >> 4) * 4;

    f32x4 acc[4];
    #pragma unroll
    for (int ct = 0; ct < 4; ++ct) acc[ct] = (f32x4){0.f, 0.f, 0.f, 0.f};

    f4v vals[4];
    auto load_tile = [&](int kt) {
        const int k4 = kt * 64 + ch;
        #pragma unroll
        for (int i = 0; i < 4; ++i) {
            const int row = row0 + i * 16 + rsub;
            f4v v = (f4v){0.f, 0.f, 0.f, 0.f};
            if (row < n && k4 < Ks) {
                if (k4 < 64)       v = ld4(id_emb + (size_t)row * 64 + k4);
                else if (k4 < 364) v = ld4(wordvec + (size_t)row * 300 + (k4 - 64));
                else               v = ld4(sentence + (size_t)row * 768 + (k4 - 364));
            }
            vals[i] = v;
        }
    };

    const int NT = Kpad / 64;
    load_tile(0);
    for (int kt = 0; kt < NT; ++kt) {
        __syncthreads();
        #pragma unroll
        for (int i = 0; i < 4; ++i) {
            const int r = i * 16 + rsub;
            uint2 pk;
            pk.x = pk2(vals[i].x, vals[i].y);
            pk.y = pk2(vals[i].z, vals[i].w);
            *(uint2*)&aS[r][ch] = pk;
        }
        __syncthreads();
        if (kt + 1 < NT) load_tile(kt + 1);
        #pragma unroll
        for (int ks = 0; ks < 2; ++ks) {
            const bf16x8 af = *(const bf16x8*)&aS[w16 + l15][ks * 32 + hi8];
            #pragma unroll
            for (int ct = 0; ct < 4; ++ct) {
                const bf16x8 bfr = *(const bf16x8*)&WT[(size_t)(ct * 16 + l15) * Kpad
                                                      + kt * 64 + ks * 32 + hi8];
                acc[ct] = __builtin_amdgcn_mfma_f32_16x16x32_bf16(af, bfr, acc[ct], 0, 0, 0);
            }
        }
    }

    // epilogue: + x_partial, write bf16
    #pragma unroll
    for (int ct = 0; ct < 4; ++ct) {
        const int c = ct * 16 + l15;
        #pragma unroll
        for (int j = 0; j < 4; ++j) {
            const int row = row0 + w16 + g4 + j;
            if (row < n) {
                const size_t gi = (size_t)(row_off + row) * 64 + c;
                x_out[gi] = bf16r(acc[ct][j] + bfu(xp[gi]));
            }
        }
    }
}

// ---------------------------------------------------------------------------
// GNN layer via MFMA. 64 rows/block. (unchanged)
// ---------------------------------------------------------------------------
__global__ __launch_bounds__(256, 6) void gnn_layer_kernel(
    const unsigned short* __restrict__ x, const int* __restrict__ nbr,
    const unsigned short* __restrict__ VT, const unsigned short* __restrict__ W2T,
    const float* __restrict__ vb, const float* __restrict__ wb,
    void* __restrict__ outp, int finalize)
{
    __shared__ __align__(16) unsigned short mS[64][72];
    __shared__ int nbs[64][8];
    const int t = threadIdx.x;
    const int row0 = blockIdx.x * 64;

    for (int e = t; e < 512; e += 256) nbs[e >> 3][e & 7] = nbr[row0 * 8 + e];
    __syncthreads();

    {   // neighbor mean -> mS (bf16)
        const int r = t >> 2, c16 = (t & 3) * 16;
        float s[16];
        #pragma unroll
        for (int i = 0; i < 16; ++i) s[i] = 0.f;
        #pragma unroll
        for (int m = 0; m < 8; ++m) {
            const unsigned short* p = x + (size_t)nbs[r][m] * 64 + c16;
            const uint4 q0 = *(const uint4*)p;
            const uint4 q1 = *(const uint4*)(p + 8);
            s[0] += bfu(q0.x & 0xffff); s[1] += bfu(q0.x >> 16);
            s[2] += bfu(q0.y & 0xffff); s[3] += bfu(q0.y >> 16);
            s[4] += bfu(q0.z & 0xffff); s[5] += bfu(q0.z >> 16);
            s[6] += bfu(q0.w & 0xffff); s[7] += bfu(q0.w >> 16);
            s[8] += bfu(q1.x & 0xffff); s[9] += bfu(q1.x >> 16);
            s[10] += bfu(q1.y & 0xffff); s[11] += bfu(q1.y >> 16);
            s[12] += bfu(q1.z & 0xffff); s[13] += bfu(q1.z >> 16);
            s[14] += bfu(q1.w & 0xffff); s[15] += bfu(q1.w >> 16);
        }
        uint4 o0, o1;
        o0.x = pk2(s[0] * 0.125f, s[1] * 0.125f);
        o0.y = pk2(s[2] * 0.125f, s[3] * 0.125f);
        o0.z = pk2(s[4] * 0.125f, s[5] * 0.125f);
        o0.w = pk2(s[6] * 0.125f, s[7] * 0.125f);
        o1.x = pk2(s[8] * 0.125f, s[9] * 0.125f);
        o1.y = pk2(s[10] * 0.125f, s[11] * 0.125f);
        o1.z = pk2(s[12] * 0.125f, s[13] * 0.125f);
        o1.w = pk2(s[14] * 0.125f, s[15] * 0.125f);
        *(uint4*)&mS[r][c16] = o0;
        *(uint4*)&mS[r][c16 + 8] = o1;
    }
    __syncthreads();

    const int lane = t & 63;
    const int w16 = (t >> 6) * 16;
    const int l15 = lane & 15;
    const int hi8 = (lane >> 4) * 8;
    const int g4  = (lane >> 4) * 4;

    f32x4 ag[4];
    #pragma unroll
    for (int ct = 0; ct < 4; ++ct) ag[ct] = (f32x4){0.f, 0.f, 0.f, 0.f};
    #pragma unroll
    for (int ks = 0; ks < 2; ++ks) {
        const bf16x8 af = *(const bf16x8*)&mS[w16 + l15][ks * 32 + hi8];
        #pragma unroll
        for (int ct = 0; ct < 4; ++ct) {
            const bf16x8 bfr = *(const bf16x8*)&VT[(ct * 16 + l15) * 64 + ks * 32 + hi8];
            ag[ct] = __builtin_amdgcn_mfma_f32_16x16x32_bf16(af, bfr, ag[ct], 0, 0, 0);
        }
    }
    __syncthreads();
    #pragma unroll
    for (int ct = 0; ct < 4; ++ct) {
        const int c = ct * 16 + l15;
        const float b = vb[c];
        #pragma unroll
        for (int j = 0; j < 4; ++j)
            mS[w16 + g4 + j][c] = bf16r(ag[ct][j] + b);
    }
    __syncthreads();

    f32x4 acc[4];
    #pragma unroll
    for (int ct = 0; ct < 4; ++ct) acc[ct] = (f32x4){0.f, 0.f, 0.f, 0.f};
    #pragma unroll
    for (int ks = 0; ks < 4; ++ks) {
        bf16x8 af;
        if (ks < 2) af = *(const bf16x8*)&x[(size_t)(row0 + w16 + l15) * 64 + ks * 32 + hi8];
        else        af = *(const bf16x8*)&mS[w16 + l15][(ks - 2) * 32 + hi8];
        #pragma unroll
        for (int ct = 0; ct < 4; ++ct) {
            const bf16x8 bfr = *(const bf16x8*)&W2T[(ct * 16 + l15) * 128 + ks * 32 + hi8];
            acc[ct] = __builtin_amdgcn_mfma_f32_16x16x32_bf16(af, bfr, acc[ct], 0, 0, 0);
        }
    }

    if (!finalize) {
        unsigned short* xo = (unsigned short*)outp;
        #pragma unroll
        for (int ct = 0; ct < 4; ++ct) {
            const int c = ct * 16 + l15;
            const float b = wb[c];
            #pragma unroll
            for (int j = 0; j < 4; ++j)
                xo[(size_t)(row0 + w16 + g4 + j) * 64 + c] = bf16r(fmaxf(acc[ct][j] + b, 0.f));
        }
    } else {
        float* fo = (float*)outp;
        float vc[4][4], ss[4];
        #pragma unroll
        for (int j = 0; j < 4; ++j) ss[j] = 0.f;
        #pragma unroll
        for (int ct = 0; ct < 4; ++ct) {
            const float b = wb[ct * 16 + l15];
            #pragma unroll
            for (int j = 0; j < 4; ++j) {
                vc[ct][j] = acc[ct][j] + b;
                ss[j] += vc[ct][j] * vc[ct][j];
            }
        }
        #pragma unroll
        for (int m = 1; m < 16; m <<= 1) {
            #pragma unroll
            for (int j = 0; j < 4; ++j) ss[j] += __shfl_xor(ss[j], m, 64);
        }
        #pragma unroll
        for (int j = 0; j < 4; ++j) ss[j] = 1.f / fmaxf(sqrtf(ss[j]), 1e-12f);
        #pragma unroll
        for (int ct = 0; ct < 4; ++ct) {
            const int c = ct * 16 + l15;
            #pragma unroll
            for (int j = 0; j < 4; ++j)
                fo[(size_t)(row0 + w16 + g4 + j) * 64 + c] = vc[ct][j] * ss[j];
        }
    }
}

extern "C" void kernel_launch(void* const* d_in, const int* in_sizes, int n_in,
                              void* d_out, int out_size, void* d_ws, size_t ws_size,
                              hipStream_t stream) {
    const float* user_id_emb        = (const float*)d_in[0];
    const float* item_id_emb        = (const float*)d_in[1];
    const float* user_feat_table    = (const float*)d_in[2];
    const float* item_feat_table    = (const float*)d_in[3];
    const float* word_emb           = (const float*)d_in[4];
    const float* user_numeric       = (const float*)d_in[5];
    const float* item_numeric       = (const float*)d_in[6];
    const float* user_word_embedding= (const float*)d_in[7];
    const float* item_word_embedding= (const float*)d_in[8];
    const float* item_sentence_emb  = (const float*)d_in[9];
    const float* user_num_W         = (const float*)d_in[10];
    const float* user_num_b         = (const float*)d_in[11];
    const float* item_num_W         = (const float*)d_in[12];
    const float* item_num_b         = (const float*)d_in[13];
    const float* user_proj_W        = (const float*)d_in[14];
    const float* user_proj_b        = (const float*)d_in[15];
    const float* item_proj_W        = (const float*)d_in[16];
    const float* item_proj_b        = (const float*)d_in[17];
    const float* w_W                = (const float*)d_in[18];
    const float* w_b                = (const float*)d_in[19];
    const float* v_W                = (const float*)d_in[20];
    const float* v_b                = (const float*)d_in[21];
    const int*   user_feat_idx      = (const int*)d_in[22];
    const int*   item_feat_idx      = (const int*)d_in[23];
    const int*   user_text_idx      = (const int*)d_in[24];
    const int*   item_text_idx      = (const int*)d_in[25];
    const int*   neighbors          = (const int*)d_in[26];

    // d_ws: x0 [NTOT*64 bf16] | region B = projected tables, later x1
    unsigned short* x0 = (unsigned short*)d_ws;
    unsigned short* x1 = x0 + (size_t)NTOT * 64;
    unsigned short* Pfu = x1;                       // 5000*64
    unsigned short* Pfi = Pfu + 5000 * 64;          // 10000*64
    unsigned short* Pwu = Pfi + 10000 * 64;         // 3 x 30000*64 contiguous
    unsigned short* Pwi = Pwu + 3 * 30000 * 64;     // 3 x 30000*64

    // d_out: x_partial front [NTOT*64 bf16]; weights in tail
    unsigned short* xp = (unsigned short*)d_out;
    const size_t tail_elems = (size_t)64 * (KSUP + KSIP + 64 + 128);
    unsigned short* WTu = (unsigned short*)((char*)d_out + (size_t)out_size * 4
                                            - tail_elems * 2);
    unsigned short* WTi = WTu + 64 * KSUP;
    unsigned short* VT0 = WTi + 64 * KSIP;
    unsigned short* W20 = VT0 + 64 * 64;
    // layer-1 weights re-prepped into dead x0 region after L0
    unsigned short* VT1 = (unsigned short*)d_ws;
    unsigned short* W21 = VT1 + 64 * 64;

    // 1. projected tables (scales folded)
    proj_tab<<<(5000 + 3) / 4, 256, 0, stream>>>(user_feat_table, user_proj_W,
                                                 64, 64, 0.2f, Pfu, 5000);
    proj_tab<<<(10000 + 3) / 4, 256, 0, stream>>>(item_feat_table, item_proj_W,
                                                  64, 64, 0.2f, Pfi, 10000);
    for (int f = 0; f < 3; ++f) {
        proj_tab<<<7500, 256, 0, stream>>>(word_emb, user_proj_W,
                                           128 + 32 * f, 32, 0.125f,
                                           Pwu + (size_t)f * 30000 * 64, 30000);
        proj_tab<<<7500, 256, 0, stream>>>(word_emb, item_proj_W,
                                           128 + 32 * f, 32, 0.125f,
                                           Pwi + (size_t)f * 30000 * 64, 30000);
    }
    // 2. stream-slice weights + layer-0 weights
    prep_wt_remap<<<dim3((KSUP + 255) / 256, 64), 256, 0, stream>>>(user_proj_W, WTu, KSU, KSUP);
    prep_wt_remap<<<dim3((KSIP + 255) / 256, 64), 256, 0, stream>>>(item_proj_W, WTi, KSI, KSIP);
    prep_wt<<<dim3(1, 64), 256, 0, stream>>>(v_W, VT0, 64, 64);
    prep_wt<<<dim3(1, 64), 256, 0, stream>>>(w_W, W20, 128, 128);

    // 3. gather-sum of projected tables -> x_partial
    gather_psum<<<NTOT / 4, 256, 0, stream>>>(
        Pfu, Pfi, Pwu, Pwi,
        user_feat_idx, item_feat_idx, user_text_idx, item_text_idx,
        user_numeric, item_numeric, user_num_W, item_num_W,
        user_proj_b, item_proj_b, user_num_b, item_num_b, xp);

    // 4. pure-stream GEMMs -> x0
    stream_gemm<<<(NU + 63) / 64, 256, 0, stream>>>(
        user_id_emb, user_word_embedding, nullptr, WTu, xp, x0, NU, KSU, KSUP, 0);
    stream_gemm<<<(NI + 63) / 64, 256, 0, stream>>>(
        item_id_emb, item_word_embedding, item_sentence_emb, WTi, xp, x0,
        NI, KSI, KSIP, NU);

    // 5. layer 0: x0 -> x1 (overwrites dead tables)
    gnn_layer_kernel<<<NTOT / 64, 256, 0, stream>>>(
        x0, neighbors, VT0, W20, v_b, w_b, x1, 0);

    // 6. layer-1 weights into dead x0 region
    prep_wt<<<dim3(1, 64), 256, 0, stream>>>(v_W + 64 * 64, VT1, 64, 64);
    prep_wt<<<dim3(1, 64), 256, 0, stream>>>(w_W + 128 * 64, W21, 128, 128);

    // 7. layer 1 + fused normalize: x1 -> d_out
    gnn_layer_kernel<<<NTOT / 64, 256, 0, stream>>>(
        x1, neighbors, VT1, W21, v_b + 64, w_b + 64, d_out, 1);
}

// Round 14
// 586.101 us; speedup vs baseline: 1.6460x; 1.6460x over previous
//
#include <hip/hip_runtime.h>

typedef __attribute__((ext_vector_type(8))) short bf16x8;
typedef __attribute__((ext_vector_type(4))) float f32x4;
typedef __attribute__((ext_vector_type(4))) float f4v;

#define NU 150000
#define NI 50000
#define NTOT 200000
#define KU 524
#define KUP 576
#define KI 1292
#define KIP 1344
#define UBLK 2344           // user blocks needed
#define IBLK 782            // item blocks needed
#define GBLK (4 * IBLK)     // merged grid: 3:1 interleave, 3128 blocks

__device__ __forceinline__ f4v ld4(const float* p) { return *(const f4v*)p; }

__device__ __forceinline__ unsigned short bf16r(float x) {
    unsigned u = __float_as_uint(x);
    u += 0x7fff + ((u >> 16) & 1);
    return (unsigned short)(u >> 16);
}
__device__ __forceinline__ unsigned pk2(float lo, float hi) {
    unsigned a = __float_as_uint(lo), b = __float_as_uint(hi);
    a += 0x7fff + ((a >> 16) & 1);
    b += 0x7fff + ((b >> 16) & 1);
    return (a >> 16) | (b & 0xffff0000u);
}
__device__ __forceinline__ float bfu(unsigned short u) {
    return __uint_as_float((unsigned)u << 16);
}

// W [K][64] fp32 -> WT [64][Kpad] bf16 (zero-padded K)
__global__ void prep_wt(const float* __restrict__ src, unsigned short* __restrict__ dst,
                        int K, int Kpad) {
    const int c = blockIdx.y;
    const int k = blockIdx.x * 256 + threadIdx.x;
    if (k >= Kpad) return;
    dst[(size_t)c * Kpad + k] = (k < K) ? bf16r(src[(size_t)k * 64 + c]) : (unsigned short)0;
}

// ---------------------------------------------------------------------------
// Text-mean pre-pass, wave-per-node layout (R8, proven).
// ---------------------------------------------------------------------------
__global__ __launch_bounds__(256, 8) void txt_mean_kernel(
    const float* __restrict__ word_emb,
    const int* __restrict__ u_text_idx, const int* __restrict__ i_text_idx,
    unsigned short* __restrict__ stage)
{
    __shared__ __align__(16) unsigned short st[4][96];   // contiguous 768B
    const int wid  = threadIdx.x >> 6;
    const int lane = threadIdx.x & 63;
    const int node = blockIdx.x * 4 + wid;               // grid exact: NTOT/4
    const int c = lane & 31, h = lane >> 5;
    const int* tip = (node < NU) ? (u_text_idx + (size_t)node * 24)
                                 : (i_text_idx + (size_t)(node - NU) * 24);
    float s[3];
    #pragma unroll
    for (int f = 0; f < 3; ++f) {
        float a = 0.f;
        #pragma unroll
        for (int rr = 0; rr < 4; ++rr) {
            const int idx = tip[f * 8 + rr * 2 + h];     // 32-lane broadcast load
            a += word_emb[(size_t)idx * 32 + c];         // half-wave = full row
        }
        s[f] = a;
    }
    #pragma unroll
    for (int f = 0; f < 3; ++f) s[f] += __shfl_xor(s[f], 32, 64);
    if (h == 0) {
        #pragma unroll
        for (int f = 0; f < 3; ++f) st[wid][f * 32 + c] = bf16r(s[f] * 0.125f);
    }
    __syncthreads();
    if (threadIdx.x < 48) {
        const uint4 v = *(const uint4*)&st[0][threadIdx.x * 8];
        *(uint4*)(stage + (size_t)blockIdx.x * 384 + threadIdx.x * 8) = v;
    }
}

// ---------------------------------------------------------------------------
// MERGED node-feature build + projection (user+item in one grid, 3:1 block
// interleave so item blocks co-reside with user blocks and fill their idle
// latency slots). Body = the proven R10 2-barrier pipeline with contiguous
// staging lane-map (best measured: 199us user / 65us item sequential).
// ---------------------------------------------------------------------------
__global__ __launch_bounds__(256, 6) void node_init_kernel(
    const float* __restrict__ u_id, const float* __restrict__ i_id,
    const float* __restrict__ u_ft, const float* __restrict__ i_ft,
    const unsigned short* __restrict__ txt_stage,
    const float* __restrict__ u_num, const float* __restrict__ i_num,
    const float* __restrict__ u_wv, const float* __restrict__ i_wv,
    const float* __restrict__ sentence,
    const int* __restrict__ u_fi, const int* __restrict__ i_fi,
    const unsigned short* __restrict__ WTu, const unsigned short* __restrict__ WTi,
    const float* __restrict__ u_pb, const float* __restrict__ i_pb,
    const float* __restrict__ u_nw, const float* __restrict__ i_nw,
    const float* __restrict__ u_nb, const float* __restrict__ i_nb,
    unsigned short* __restrict__ x_out)
{
    __shared__ __align__(16) unsigned short aS[64][72];
    __shared__ unsigned short fiS[64][5];
    __shared__ float nmrS[64][10];

    const int bid = blockIdx.x;
    const bool isu = (bid & 3) != 3;               // 3:1 user:item interleave
    const int lb  = isu ? 3 * (bid >> 2) + (bid & 3) : (bid >> 2);
    const int row0 = lb * 64;

    const float* id_emb     = isu ? u_id : i_id;
    const float* feat_table = isu ? u_ft : i_ft;
    const float* numeric    = isu ? u_num : i_num;
    const float* wordvec    = isu ? u_wv : i_wv;
    const int*   feat_idx   = isu ? u_fi : i_fi;
    const unsigned short* WT = isu ? WTu : WTi;
    const float* projb = isu ? u_pb : i_pb;
    const float* numW  = isu ? u_nw : i_nw;
    const float* numb  = isu ? u_nb : i_nb;
    const int n    = isu ? NU : NI;
    const int Ktot = isu ? KU : KI;
    const int Kpad = isu ? KUP : KIP;
    const int row_off = isu ? 0 : NU;

    const int t = threadIdx.x;

    for (int e = t; e < 64 * 5; e += 256) {
        const int r = e / 5, j = e - r * 5, row = row0 + r;
        fiS[r][j] = (row < n) ? (unsigned short)feat_idx[row * 5 + j] : (unsigned short)0;
    }
    for (int e = t; e < 64 * 10; e += 256) {
        const int r = e / 10, j = e - r * 10, row = row0 + r;
        nmrS[r][j] = (row < n) ? numeric[(size_t)row * 10 + j] : 0.f;
    }
    __syncthreads();

    const int ch  = (t & 15) * 4;      // float offset within k-tile
    const int rsub = t >> 4;           // row-sub within 16-row group

    const int lane = t & 63;
    const int w16 = (t >> 6) * 16;
    const int l15 = lane & 15;
    const int hi8 = (lane >> 4) * 8;
    const int g4  = (lane >> 4) * 4;

    f32x4 acc[4];
    #pragma unroll
    for (int ct = 0; ct < 4; ++ct) acc[ct] = (f32x4){0.f, 0.f, 0.f, 0.f};

    f4v vals[4];
    auto load_tile = [&](int kt) {
        const int k4 = kt * 64 + ch;
        #pragma unroll
        for (int i = 0; i < 4; ++i) {
            const int r = i * 16 + rsub;       // block-local row
            const int row = row0 + r;
            f4v v = (f4v){0.f, 0.f, 0.f, 0.f};
            if (row < n && k4 < Ktot) {
                if (k4 >= 524) {
                    v = ld4(sentence + (size_t)row * 768 + (k4 - 524));
                } else if (k4 >= 224) {
                    v = ld4(wordvec + (size_t)row * 300 + (k4 - 224));
                } else if (k4 >= 128) {
                    const ushort4 q = *(const ushort4*)(txt_stage
                                        + (size_t)(row_off + row) * 96 + (k4 - 128));
                    v.x = bfu(q.x); v.y = bfu(q.y); v.z = bfu(q.z); v.w = bfu(q.w);
                } else if (k4 >= 64) {
                    const int c = k4 - 64;
                    f4v s = (f4v){0.f, 0.f, 0.f, 0.f};
                    #pragma unroll
                    for (int m = 0; m < 5; ++m) {
                        const f4v g = ld4(feat_table + (size_t)fiS[r][m] * 64 + c);
                        s.x += g.x; s.y += g.y; s.z += g.z; s.w += g.w;
                    }
                    v.x = s.x * 0.2f; v.y = s.y * 0.2f;
                    v.z = s.z * 0.2f; v.w = s.w * 0.2f;
                } else {
                    v = ld4(id_emb + (size_t)row * 64 + k4);
                }
            }
            vals[i] = v;
        }
    };

    const int NT = Kpad / 64;
    load_tile(0);
    for (int kt = 0; kt < NT; ++kt) {
        __syncthreads();   // previous tile's MFMA readers done
        #pragma unroll
        for (int i = 0; i < 4; ++i) {
            const int r = i * 16 + rsub;
            uint2 pk;
            pk.x = pk2(vals[i].x, vals[i].y);
            pk.y = pk2(vals[i].z, vals[i].w);
            *(uint2*)&aS[r][ch] = pk;
        }
        __syncthreads();   // tile visible
        if (kt + 1 < NT) load_tile(kt + 1);   // prefetch, hidden under MFMA
        #pragma unroll
        for (int ks = 0; ks < 2; ++ks) {
            const bf16x8 af = *(const bf16x8*)&aS[w16 + l15][ks * 32 + hi8];
            #pragma unroll
            for (int ct = 0; ct < 4; ++ct) {
                const bf16x8 bfr = *(const bf16x8*)&WT[(size_t)(ct * 16 + l15) * Kpad
                                                      + kt * 64 + ks * 32 + hi8];
                acc[ct] = __builtin_amdgcn_mfma_f32_16x16x32_bf16(af, bfr, acc[ct], 0, 0, 0);
            }
        }
    }

    // epilogue: proj bias + numeric side-GEMM + num bias, write bf16 (cached)
    #pragma unroll
    for (int ct = 0; ct < 4; ++ct) {
        const int c = ct * 16 + l15;
        const float pb = projb[c] + numb[c];
        float wn[10];
        #pragma unroll
        for (int m = 0; m < 10; ++m) wn[m] = numW[m * 64 + c];
        #pragma unroll
        for (int j = 0; j < 4; ++j) {
            const int r = w16 + g4 + j;
            const int row = row0 + r;
            if (row < n) {
                float s = acc[ct][j] + pb;
                #pragma unroll
                for (int m = 0; m < 10; ++m) s += nmrS[r][m] * wn[m];
                x_out[(size_t)(row_off + row) * 64 + c] = bf16r(s);
            }
        }
    }
}

// ---------------------------------------------------------------------------
// GNN layer via MFMA. 64 rows/block. (unchanged from the 492us R11 config)
// ---------------------------------------------------------------------------
__global__ __launch_bounds__(256, 6) void gnn_layer_kernel(
    const unsigned short* __restrict__ x, const int* __restrict__ nbr,
    const unsigned short* __restrict__ VT, const unsigned short* __restrict__ W2T,
    const float* __restrict__ vb, const float* __restrict__ wb,
    void* __restrict__ outp, int finalize)
{
    __shared__ __align__(16) unsigned short mS[64][72];
    __shared__ int nbs[64][8];
    const int t = threadIdx.x;
    const int row0 = blockIdx.x * 64;

    for (int e = t; e < 512; e += 256) nbs[e >> 3][e & 7] = nbr[row0 * 8 + e];
    __syncthreads();

    {   // neighbor mean -> mS (bf16)
        const int r = t >> 2, c16 = (t & 3) * 16;
        float s[16];
        #pragma unroll
        for (int i = 0; i < 16; ++i) s[i] = 0.f;
        #pragma unroll
        for (int m = 0; m < 8; ++m) {
            const unsigned short* p = x + (size_t)nbs[r][m] * 64 + c16;
            const uint4 q0 = *(const uint4*)p;
            const uint4 q1 = *(const uint4*)(p + 8);
            s[0] += bfu(q0.x & 0xffff); s[1] += bfu(q0.x >> 16);
            s[2] += bfu(q0.y & 0xffff); s[3] += bfu(q0.y >> 16);
            s[4] += bfu(q0.z & 0xffff); s[5] += bfu(q0.z >> 16);
            s[6] += bfu(q0.w & 0xffff); s[7] += bfu(q0.w >> 16);
            s[8] += bfu(q1.x & 0xffff); s[9] += bfu(q1.x >> 16);
            s[10] += bfu(q1.y & 0xffff); s[11] += bfu(q1.y >> 16);
            s[12] += bfu(q1.z & 0xffff); s[13] += bfu(q1.z >> 16);
            s[14] += bfu(q1.w & 0xffff); s[15] += bfu(q1.w >> 16);
        }
        uint4 o0, o1;
        o0.x = pk2(s[0] * 0.125f, s[1] * 0.125f);
        o0.y = pk2(s[2] * 0.125f, s[3] * 0.125f);
        o0.z = pk2(s[4] * 0.125f, s[5] * 0.125f);
        o0.w = pk2(s[6] * 0.125f, s[7] * 0.125f);
        o1.x = pk2(s[8] * 0.125f, s[9] * 0.125f);
        o1.y = pk2(s[10] * 0.125f, s[11] * 0.125f);
        o1.z = pk2(s[12] * 0.125f, s[13] * 0.125f);
        o1.w = pk2(s[14] * 0.125f, s[15] * 0.125f);
        *(uint4*)&mS[r][c16] = o0;
        *(uint4*)&mS[r][c16 + 8] = o1;
    }
    __syncthreads();

    const int lane = t & 63;
    const int w16 = (t >> 6) * 16;
    const int l15 = lane & 15;
    const int hi8 = (lane >> 4) * 8;
    const int g4  = (lane >> 4) * 4;

    f32x4 ag[4];
    #pragma unroll
    for (int ct = 0; ct < 4; ++ct) ag[ct] = (f32x4){0.f, 0.f, 0.f, 0.f};
    #pragma unroll
    for (int ks = 0; ks < 2; ++ks) {
        const bf16x8 af = *(const bf16x8*)&mS[w16 + l15][ks * 32 + hi8];
        #pragma unroll
        for (int ct = 0; ct < 4; ++ct) {
            const bf16x8 bfr = *(const bf16x8*)&VT[(ct * 16 + l15) * 64 + ks * 32 + hi8];
            ag[ct] = __builtin_amdgcn_mfma_f32_16x16x32_bf16(af, bfr, ag[ct], 0, 0, 0);
        }
    }
    __syncthreads();
    #pragma unroll
    for (int ct = 0; ct < 4; ++ct) {
        const int c = ct * 16 + l15;
        const float b = vb[c];
        #pragma unroll
        for (int j = 0; j < 4; ++j)
            mS[w16 + g4 + j][c] = bf16r(ag[ct][j] + b);
    }
    __syncthreads();

    f32x4 acc[4];
    #pragma unroll
    for (int ct = 0; ct < 4; ++ct) acc[ct] = (f32x4){0.f, 0.f, 0.f, 0.f};
    #pragma unroll
    for (int ks = 0; ks < 4; ++ks) {
        bf16x8 af;
        if (ks < 2) af = *(const bf16x8*)&x[(size_t)(row0 + w16 + l15) * 64 + ks * 32 + hi8];
        else        af = *(const bf16x8*)&mS[w16 + l15][(ks - 2) * 32 + hi8];
        #pragma unroll
        for (int ct = 0; ct < 4; ++ct) {
            const bf16x8 bfr = *(const bf16x8*)&W2T[(ct * 16 + l15) * 128 + ks * 32 + hi8];
            acc[ct] = __builtin_amdgcn_mfma_f32_16x16x32_bf16(af, bfr, acc[ct], 0, 0, 0);
        }
    }

    if (!finalize) {
        unsigned short* xo = (unsigned short*)outp;
        #pragma unroll
        for (int ct = 0; ct < 4; ++ct) {
            const int c = ct * 16 + l15;
            const float b = wb[c];
            #pragma unroll
            for (int j = 0; j < 4; ++j)
                xo[(size_t)(row0 + w16 + g4 + j) * 64 + c] = bf16r(fmaxf(acc[ct][j] + b, 0.f));
        }
    } else {
        float* fo = (float*)outp;
        float vc[4][4], ss[4];
        #pragma unroll
        for (int j = 0; j < 4; ++j) ss[j] = 0.f;
        #pragma unroll
        for (int ct = 0; ct < 4; ++ct) {
            const float b = wb[ct * 16 + l15];
            #pragma unroll
            for (int j = 0; j < 4; ++j) {
                vc[ct][j] = acc[ct][j] + b;
                ss[j] += vc[ct][j] * vc[ct][j];
            }
        }
        #pragma unroll
        for (int m = 1; m < 16; m <<= 1) {
            #pragma unroll
            for (int j = 0; j < 4; ++j) ss[j] += __shfl_xor(ss[j], m, 64);
        }
        #pragma unroll
        for (int j = 0; j < 4; ++j) ss[j] = 1.f / fmaxf(sqrtf(ss[j]), 1e-12f);
        #pragma unroll
        for (int ct = 0; ct < 4; ++ct) {
            const int c = ct * 16 + l15;
            #pragma unroll
            for (int j = 0; j < 4; ++j)
                fo[(size_t)(row0 + w16 + g4 + j) * 64 + c] = vc[ct][j] * ss[j];
        }
    }
}

extern "C" void kernel_launch(void* const* d_in, const int* in_sizes, int n_in,
                              void* d_out, int out_size, void* d_ws, size_t ws_size,
                              hipStream_t stream) {
    const float* user_id_emb        = (const float*)d_in[0];
    const float* item_id_emb        = (const float*)d_in[1];
    const float* user_feat_table    = (const float*)d_in[2];
    const float* item_feat_table    = (const float*)d_in[3];
    const float* word_emb           = (const float*)d_in[4];
    const float* user_numeric       = (const float*)d_in[5];
    const float* item_numeric       = (const float*)d_in[6];
    const float* user_word_embedding= (const float*)d_in[7];
    const float* item_word_embedding= (const float*)d_in[8];
    const float* item_sentence_emb  = (const float*)d_in[9];
    const float* user_num_W         = (const float*)d_in[10];
    const float* user_num_b         = (const float*)d_in[11];
    const float* item_num_W         = (const float*)d_in[12];
    const float* item_num_b         = (const float*)d_in[13];
    const float* user_proj_W        = (const float*)d_in[14];
    const float* user_proj_b        = (const float*)d_in[15];
    const float* item_proj_W        = (const float*)d_in[16];
    const float* item_proj_b        = (const float*)d_in[17];
    const float* w_W                = (const float*)d_in[18];
    const float* w_b                = (const float*)d_in[19];
    const float* v_W                = (const float*)d_in[20];
    const float* v_b                = (const float*)d_in[21];
    const int*   user_feat_idx      = (const int*)d_in[22];
    const int*   item_feat_idx      = (const int*)d_in[23];
    const int*   user_text_idx      = (const int*)d_in[24];
    const int*   item_text_idx      = (const int*)d_in[25];
    const int*   neighbors          = (const int*)d_in[26];

    // ws layout (bf16): x0 [NTOT][64], x1 [NTOT][64]
    unsigned short* x0 = (unsigned short*)d_ws;
    unsigned short* x1 = x0 + (size_t)NTOT * 64;

    // d_out FRONT: text-mean staging [NTOT][96] bf16 (38.4 MB)
    unsigned short* txt_stage = (unsigned short*)d_out;
    // d_out TAIL: bf16 weights (270 KB)
    const size_t prep_bytes = 2ull * 64 * (KUP + KIP + 64 + 128);
    char* WTbase = (char*)d_out + (size_t)out_size * 4 - prep_bytes;
    unsigned short* WTu = (unsigned short*)WTbase;
    unsigned short* WTi = WTu + 64 * KUP;
    unsigned short* VT0 = WTi + 64 * KIP;
    unsigned short* W20 = VT0 + 64 * 64;
    // layer-1 weights re-prepped into dead x0 region after L0
    unsigned short* VT1 = (unsigned short*)d_ws;
    unsigned short* W21 = VT1 + 64 * 64;

    prep_wt<<<dim3((KUP + 255) / 256, 64), 256, 0, stream>>>(user_proj_W, WTu, KU, KUP);
    prep_wt<<<dim3((KIP + 255) / 256, 64), 256, 0, stream>>>(item_proj_W, WTi, KI, KIP);
    prep_wt<<<dim3(1, 64), 256, 0, stream>>>(v_W, VT0, 64, 64);
    prep_wt<<<dim3(1, 64), 256, 0, stream>>>(w_W, W20, 128, 128);

    // text-mean pre-pass (wave-per-node coalesced gather)
    txt_mean_kernel<<<NTOT / 4, 256, 0, stream>>>(
        word_emb, user_text_idx, item_text_idx, txt_stage);

    // merged user+item node init (3:1 interleaved grid)
    node_init_kernel<<<GBLK, 256, 0, stream>>>(
        user_id_emb, item_id_emb, user_feat_table, item_feat_table, txt_stage,
        user_numeric, item_numeric, user_word_embedding, item_word_embedding,
        item_sentence_emb, user_feat_idx, item_feat_idx, WTu, WTi,
        user_proj_b, item_proj_b, user_num_W, item_num_W,
        user_num_b, item_num_b, x0);

    // layer 0: x0 -> x1 (relu, bf16)
    gnn_layer_kernel<<<NTOT / 64, 256, 0, stream>>>(
        x0, neighbors, VT0, W20, v_b, w_b, x1, 0);

    // re-prep layer-1 weights into dead x0 region
    prep_wt<<<dim3(1, 64), 256, 0, stream>>>(v_W + 64 * 64, VT1, 64, 64);
    prep_wt<<<dim3(1, 64), 256, 0, stream>>>(w_W + 128 * 64, W21, 128, 128);

    // layer 1 + fused normalize: x1 -> d_out (fp32, overwrites staging+weights)
    gnn_layer_kernel<<<NTOT / 64, 256, 0, stream>>>(
        x1, neighbors, VT1, W21, v_b + 64, w_b + 64, d_out, 1);
}

// Round 15
// 491.851 us; speedup vs baseline: 1.9614x; 1.1916x over previous
//
#include <hip/hip_runtime.h>

typedef __attribute__((ext_vector_type(8))) short bf16x8;
typedef __attribute__((ext_vector_type(4))) float f32x4;
typedef __attribute__((ext_vector_type(4))) float f4v;

#define NU 150000
#define NI 50000
#define NTOT 200000
#define KU 524
#define KUP 576
#define KI 1292
#define KIP 1344

__device__ __forceinline__ f4v ld4(const float* p) { return *(const f4v*)p; }

__device__ __forceinline__ unsigned short bf16r(float x) {
    unsigned u = __float_as_uint(x);
    u += 0x7fff + ((u >> 16) & 1);
    return (unsigned short)(u >> 16);
}
__device__ __forceinline__ unsigned pk2(float lo, float hi) {
    unsigned a = __float_as_uint(lo), b = __float_as_uint(hi);
    a += 0x7fff + ((a >> 16) & 1);
    b += 0x7fff + ((b >> 16) & 1);
    return (a >> 16) | (b & 0xffff0000u);
}
__device__ __forceinline__ float bfu(unsigned short u) {
    return __uint_as_float((unsigned)u << 16);
}

// W [K][64] fp32 -> WT [64][Kpad] bf16 (zero-padded K)
__global__ void prep_wt(const float* __restrict__ src, unsigned short* __restrict__ dst,
                        int K, int Kpad) {
    const int c = blockIdx.y;
    const int k = blockIdx.x * 256 + threadIdx.x;
    if (k >= Kpad) return;
    dst[(size_t)c * Kpad + k] = (k < K) ? bf16r(src[(size_t)k * 64 + c]) : (unsigned short)0;
}

// ---------------------------------------------------------------------------
// Text-mean pre-pass, wave-per-node layout (R8, proven).
// ---------------------------------------------------------------------------
__global__ __launch_bounds__(256, 8) void txt_mean_kernel(
    const float* __restrict__ word_emb,
    const int* __restrict__ u_text_idx, const int* __restrict__ i_text_idx,
    unsigned short* __restrict__ stage)
{
    __shared__ __align__(16) unsigned short st[4][96];   // contiguous 768B
    const int wid  = threadIdx.x >> 6;
    const int lane = threadIdx.x & 63;
    const int node = blockIdx.x * 4 + wid;               // grid exact: NTOT/4
    const int c = lane & 31, h = lane >> 5;
    const int* tip = (node < NU) ? (u_text_idx + (size_t)node * 24)
                                 : (i_text_idx + (size_t)(node - NU) * 24);
    float s[3];
    #pragma unroll
    for (int f = 0; f < 3; ++f) {
        float a = 0.f;
        #pragma unroll
        for (int rr = 0; rr < 4; ++rr) {
            const int idx = tip[f * 8 + rr * 2 + h];     // 32-lane broadcast load
            a += word_emb[(size_t)idx * 32 + c];         // half-wave = full row
        }
        s[f] = a;
    }
    #pragma unroll
    for (int f = 0; f < 3; ++f) s[f] += __shfl_xor(s[f], 32, 64);
    if (h == 0) {
        #pragma unroll
        for (int f = 0; f < 3; ++f) st[wid][f * 32 + c] = bf16r(s[f] * 0.125f);
    }
    __syncthreads();
    if (threadIdx.x < 48) {
        const uint4 v = *(const uint4*)&st[0][threadIdx.x * 8];
        *(uint4*)(stage + (size_t)blockIdx.x * 384 + threadIdx.x * 8) = v;
    }
}

// ---------------------------------------------------------------------------
// Node-feature build + projection (best measured config: R10 2-barrier
// pipeline, contiguous staging lane-map). WT now lives in d_ws (L2-cacheable)
// instead of d_out (suspected fine-grained/uncached) -- the single change.
// ---------------------------------------------------------------------------
__global__ __launch_bounds__(256, 6) void node_init_kernel(
    const float* __restrict__ id_emb, const float* __restrict__ feat_table,
    const unsigned short* __restrict__ txt_stage, const float* __restrict__ numeric,
    const float* __restrict__ wordvec, const float* __restrict__ sentence,
    const int* __restrict__ feat_idx,
    const unsigned short* __restrict__ WT, const float* __restrict__ projb,
    const float* __restrict__ numW, const float* __restrict__ numb,
    unsigned short* __restrict__ x_out, int n, int Ktot, int Kpad, int row_off)
{
    __shared__ __align__(16) unsigned short aS[64][72];
    __shared__ unsigned short fiS[64][5];
    __shared__ float nmrS[64][10];

    const int t = threadIdx.x;
    const int row0 = blockIdx.x * 64;

    for (int e = t; e < 64 * 5; e += 256) {
        const int r = e / 5, j = e - r * 5, row = row0 + r;
        fiS[r][j] = (row < n) ? (unsigned short)feat_idx[row * 5 + j] : (unsigned short)0;
    }
    for (int e = t; e < 64 * 10; e += 256) {
        const int r = e / 10, j = e - r * 10, row = row0 + r;
        nmrS[r][j] = (row < n) ? numeric[(size_t)row * 10 + j] : 0.f;
    }
    __syncthreads();

    const int ch  = (t & 15) * 4;      // float offset within k-tile
    const int rsub = t >> 4;           // row-sub within 16-row group

    const int lane = t & 63;
    const int w16 = (t >> 6) * 16;
    const int l15 = lane & 15;
    const int hi8 = (lane >> 4) * 8;
    const int g4  = (lane >> 4) * 4;

    f32x4 acc[4];
    #pragma unroll
    for (int ct = 0; ct < 4; ++ct) acc[ct] = (f32x4){0.f, 0.f, 0.f, 0.f};

    f4v vals[4];
    auto load_tile = [&](int kt) {
        const int k4 = kt * 64 + ch;
        #pragma unroll
        for (int i = 0; i < 4; ++i) {
            const int r = i * 16 + rsub;       // block-local row
            const int row = row0 + r;
            f4v v = (f4v){0.f, 0.f, 0.f, 0.f};
            if (row < n && k4 < Ktot) {
                if (k4 >= 524) {
                    v = ld4(sentence + (size_t)row * 768 + (k4 - 524));
                } else if (k4 >= 224) {
                    v = ld4(wordvec + (size_t)row * 300 + (k4 - 224));
                } else if (k4 >= 128) {
                    const ushort4 q = *(const ushort4*)(txt_stage
                                        + (size_t)(row_off + row) * 96 + (k4 - 128));
                    v.x = bfu(q.x); v.y = bfu(q.y); v.z = bfu(q.z); v.w = bfu(q.w);
                } else if (k4 >= 64) {
                    const int c = k4 - 64;
                    f4v s = (f4v){0.f, 0.f, 0.f, 0.f};
                    #pragma unroll
                    for (int m = 0; m < 5; ++m) {
                        const f4v g = ld4(feat_table + (size_t)fiS[r][m] * 64 + c);
                        s.x += g.x; s.y += g.y; s.z += g.z; s.w += g.w;
                    }
                    v.x = s.x * 0.2f; v.y = s.y * 0.2f;
                    v.z = s.z * 0.2f; v.w = s.w * 0.2f;
                } else {
                    v = ld4(id_emb + (size_t)row * 64 + k4);
                }
            }
            vals[i] = v;
        }
    };

    const int NT = Kpad / 64;
    load_tile(0);
    for (int kt = 0; kt < NT; ++kt) {
        __syncthreads();   // previous tile's MFMA readers done
        #pragma unroll
        for (int i = 0; i < 4; ++i) {
            const int r = i * 16 + rsub;
            uint2 pk;
            pk.x = pk2(vals[i].x, vals[i].y);
            pk.y = pk2(vals[i].z, vals[i].w);
            *(uint2*)&aS[r][ch] = pk;
        }
        __syncthreads();   // tile visible
        if (kt + 1 < NT) load_tile(kt + 1);   // prefetch, hidden under MFMA
        #pragma unroll
        for (int ks = 0; ks < 2; ++ks) {
            const bf16x8 af = *(const bf16x8*)&aS[w16 + l15][ks * 32 + hi8];
            #pragma unroll
            for (int ct = 0; ct < 4; ++ct) {
                const bf16x8 bfr = *(const bf16x8*)&WT[(size_t)(ct * 16 + l15) * Kpad
                                                      + kt * 64 + ks * 32 + hi8];
                acc[ct] = __builtin_amdgcn_mfma_f32_16x16x32_bf16(af, bfr, acc[ct], 0, 0, 0);
            }
        }
    }

    // epilogue: proj bias + numeric side-GEMM + num bias, write bf16 (cached)
    #pragma unroll
    for (int ct = 0; ct < 4; ++ct) {
        const int c = ct * 16 + l15;
        const float pb = projb[c] + numb[c];
        float wn[10];
        #pragma unroll
        for (int m = 0; m < 10; ++m) wn[m] = numW[m * 64 + c];
        #pragma unroll
        for (int j = 0; j < 4; ++j) {
            const int r = w16 + g4 + j;
            const int row = row0 + r;
            if (row < n) {
                float s = acc[ct][j] + pb;
                #pragma unroll
                for (int m = 0; m < 10; ++m) s += nmrS[r][m] * wn[m];
                x_out[(size_t)(row_off + row) * 64 + c] = bf16r(s);
            }
        }
    }
}

// ---------------------------------------------------------------------------
// GNN layer via MFMA. 64 rows/block. (unchanged from the 492us config)
// ---------------------------------------------------------------------------
__global__ __launch_bounds__(256, 6) void gnn_layer_kernel(
    const unsigned short* __restrict__ x, const int* __restrict__ nbr,
    const unsigned short* __restrict__ VT, const unsigned short* __restrict__ W2T,
    const float* __restrict__ vb, const float* __restrict__ wb,
    void* __restrict__ outp, int finalize)
{
    __shared__ __align__(16) unsigned short mS[64][72];
    __shared__ int nbs[64][8];
    const int t = threadIdx.x;
    const int row0 = blockIdx.x * 64;

    for (int e = t; e < 512; e += 256) nbs[e >> 3][e & 7] = nbr[row0 * 8 + e];
    __syncthreads();

    {   // neighbor mean -> mS (bf16)
        const int r = t >> 2, c16 = (t & 3) * 16;
        float s[16];
        #pragma unroll
        for (int i = 0; i < 16; ++i) s[i] = 0.f;
        #pragma unroll
        for (int m = 0; m < 8; ++m) {
            const unsigned short* p = x + (size_t)nbs[r][m] * 64 + c16;
            const uint4 q0 = *(const uint4*)p;
            const uint4 q1 = *(const uint4*)(p + 8);
            s[0] += bfu(q0.x & 0xffff); s[1] += bfu(q0.x >> 16);
            s[2] += bfu(q0.y & 0xffff); s[3] += bfu(q0.y >> 16);
            s[4] += bfu(q0.z & 0xffff); s[5] += bfu(q0.z >> 16);
            s[6] += bfu(q0.w & 0xffff); s[7] += bfu(q0.w >> 16);
            s[8] += bfu(q1.x & 0xffff); s[9] += bfu(q1.x >> 16);
            s[10] += bfu(q1.y & 0xffff); s[11] += bfu(q1.y >> 16);
            s[12] += bfu(q1.z & 0xffff); s[13] += bfu(q1.z >> 16);
            s[14] += bfu(q1.w & 0xffff); s[15] += bfu(q1.w >> 16);
        }
        uint4 o0, o1;
        o0.x = pk2(s[0] * 0.125f, s[1] * 0.125f);
        o0.y = pk2(s[2] * 0.125f, s[3] * 0.125f);
        o0.z = pk2(s[4] * 0.125f, s[5] * 0.125f);
        o0.w = pk2(s[6] * 0.125f, s[7] * 0.125f);
        o1.x = pk2(s[8] * 0.125f, s[9] * 0.125f);
        o1.y = pk2(s[10] * 0.125f, s[11] * 0.125f);
        o1.z = pk2(s[12] * 0.125f, s[13] * 0.125f);
        o1.w = pk2(s[14] * 0.125f, s[15] * 0.125f);
        *(uint4*)&mS[r][c16] = o0;
        *(uint4*)&mS[r][c16 + 8] = o1;
    }
    __syncthreads();

    const int lane = t & 63;
    const int w16 = (t >> 6) * 16;
    const int l15 = lane & 15;
    const int hi8 = (lane >> 4) * 8;
    const int g4  = (lane >> 4) * 4;

    f32x4 ag[4];
    #pragma unroll
    for (int ct = 0; ct < 4; ++ct) ag[ct] = (f32x4){0.f, 0.f, 0.f, 0.f};
    #pragma unroll
    for (int ks = 0; ks < 2; ++ks) {
        const bf16x8 af = *(const bf16x8*)&mS[w16 + l15][ks * 32 + hi8];
        #pragma unroll
        for (int ct = 0; ct < 4; ++ct) {
            const bf16x8 bfr = *(const bf16x8*)&VT[(ct * 16 + l15) * 64 + ks * 32 + hi8];
            ag[ct] = __builtin_amdgcn_mfma_f32_16x16x32_bf16(af, bfr, ag[ct], 0, 0, 0);
        }
    }
    __syncthreads();
    #pragma unroll
    for (int ct = 0; ct < 4; ++ct) {
        const int c = ct * 16 + l15;
        const float b = vb[c];
        #pragma unroll
        for (int j = 0; j < 4; ++j)
            mS[w16 + g4 + j][c] = bf16r(ag[ct][j] + b);
    }
    __syncthreads();

    f32x4 acc[4];
    #pragma unroll
    for (int ct = 0; ct < 4; ++ct) acc[ct] = (f32x4){0.f, 0.f, 0.f, 0.f};
    #pragma unroll
    for (int ks = 0; ks < 4; ++ks) {
        bf16x8 af;
        if (ks < 2) af = *(const bf16x8*)&x[(size_t)(row0 + w16 + l15) * 64 + ks * 32 + hi8];
        else        af = *(const bf16x8*)&mS[w16 + l15][(ks - 2) * 32 + hi8];
        #pragma unroll
        for (int ct = 0; ct < 4; ++ct) {
            const bf16x8 bfr = *(const bf16x8*)&W2T[(ct * 16 + l15) * 128 + ks * 32 + hi8];
            acc[ct] = __builtin_amdgcn_mfma_f32_16x16x32_bf16(af, bfr, acc[ct], 0, 0, 0);
        }
    }

    if (!finalize) {
        unsigned short* xo = (unsigned short*)outp;
        #pragma unroll
        for (int ct = 0; ct < 4; ++ct) {
            const int c = ct * 16 + l15;
            const float b = wb[c];
            #pragma unroll
            for (int j = 0; j < 4; ++j)
                xo[(size_t)(row0 + w16 + g4 + j) * 64 + c] = bf16r(fmaxf(acc[ct][j] + b, 0.f));
        }
    } else {
        float* fo = (float*)outp;
        float vc[4][4], ss[4];
        #pragma unroll
        for (int j = 0; j < 4; ++j) ss[j] = 0.f;
        #pragma unroll
        for (int ct = 0; ct < 4; ++ct) {
            const float b = wb[ct * 16 + l15];
            #pragma unroll
            for (int j = 0; j < 4; ++j) {
                vc[ct][j] = acc[ct][j] + b;
                ss[j] += vc[ct][j] * vc[ct][j];
            }
        }
        #pragma unroll
        for (int m = 1; m < 16; m <<= 1) {
            #pragma unroll
            for (int j = 0; j < 4; ++j) ss[j] += __shfl_xor(ss[j], m, 64);
        }
        #pragma unroll
        for (int j = 0; j < 4; ++j) ss[j] = 1.f / fmaxf(sqrtf(ss[j]), 1e-12f);
        #pragma unroll
        for (int ct = 0; ct < 4; ++ct) {
            const int c = ct * 16 + l15;
            #pragma unroll
            for (int j = 0; j < 4; ++j)
                fo[(size_t)(row0 + w16 + g4 + j) * 64 + c] = vc[ct][j] * ss[j];
        }
    }
}

extern "C" void kernel_launch(void* const* d_in, const int* in_sizes, int n_in,
                              void* d_out, int out_size, void* d_ws, size_t ws_size,
                              hipStream_t stream) {
    const float* user_id_emb        = (const float*)d_in[0];
    const float* item_id_emb        = (const float*)d_in[1];
    const float* user_feat_table    = (const float*)d_in[2];
    const float* item_feat_table    = (const float*)d_in[3];
    const float* word_emb           = (const float*)d_in[4];
    const float* user_numeric       = (const float*)d_in[5];
    const float* item_numeric       = (const float*)d_in[6];
    const float* user_word_embedding= (const float*)d_in[7];
    const float* item_word_embedding= (const float*)d_in[8];
    const float* item_sentence_emb  = (const float*)d_in[9];
    const float* user_num_W         = (const float*)d_in[10];
    const float* user_num_b         = (const float*)d_in[11];
    const float* item_num_W         = (const float*)d_in[12];
    const float* item_num_b         = (const float*)d_in[13];
    const float* user_proj_W        = (const float*)d_in[14];
    const float* user_proj_b        = (const float*)d_in[15];
    const float* item_proj_W        = (const float*)d_in[16];
    const float* item_proj_b        = (const float*)d_in[17];
    const float* w_W                = (const float*)d_in[18];
    const float* w_b                = (const float*)d_in[19];
    const float* v_W                = (const float*)d_in[20];
    const float* v_b                = (const float*)d_in[21];
    const int*   user_feat_idx      = (const int*)d_in[22];
    const int*   item_feat_idx      = (const int*)d_in[23];
    const int*   user_text_idx      = (const int*)d_in[24];
    const int*   item_text_idx      = (const int*)d_in[25];
    const int*   neighbors          = (const int*)d_in[26];

    // ws layout (bf16): x0 [NTOT][64], x1 [NTOT][64]
    unsigned short* x0 = (unsigned short*)d_ws;
    unsigned short* x1 = x0 + (size_t)NTOT * 64;

    // *** H-test: node-init weights in d_ws (x1 region, dead until gnn0
    //     overwrites it) instead of the d_out tail ***
    unsigned short* WTu = x1;                    // 64*KUP  (73.7 KB)
    unsigned short* WTi = WTu + 64 * KUP;        // 64*KIP  (172 KB)

    // d_out FRONT: text-mean staging [NTOT][96] bf16 (38.4 MB)
    unsigned short* txt_stage = (unsigned short*)d_out;
    // d_out TAIL: gnn-layer-0 weights only (24 KB)
    const size_t prep_bytes = 2ull * 64 * (64 + 128);
    char* WTbase = (char*)d_out + (size_t)out_size * 4 - prep_bytes;
    unsigned short* VT0 = (unsigned short*)WTbase;
    unsigned short* W20 = VT0 + 64 * 64;
    // layer-1 weights re-prepped into dead x0 region after L0
    unsigned short* VT1 = (unsigned short*)d_ws;
    unsigned short* W21 = VT1 + 64 * 64;

    prep_wt<<<dim3((KUP + 255) / 256, 64), 256, 0, stream>>>(user_proj_W, WTu, KU, KUP);
    prep_wt<<<dim3((KIP + 255) / 256, 64), 256, 0, stream>>>(item_proj_W, WTi, KI, KIP);
    prep_wt<<<dim3(1, 64), 256, 0, stream>>>(v_W, VT0, 64, 64);
    prep_wt<<<dim3(1, 64), 256, 0, stream>>>(w_W, W20, 128, 128);

    // text-mean pre-pass (wave-per-node coalesced gather)
    txt_mean_kernel<<<NTOT / 4, 256, 0, stream>>>(
        word_emb, user_text_idx, item_text_idx, txt_stage);

    node_init_kernel<<<(NU + 63) / 64, 256, 0, stream>>>(
        user_id_emb, user_feat_table, txt_stage, user_numeric,
        user_word_embedding, nullptr, user_feat_idx,
        WTu, user_proj_b, user_num_W, user_num_b, x0, NU, KU, KUP, 0);
    node_init_kernel<<<(NI + 63) / 64, 256, 0, stream>>>(
        item_id_emb, item_feat_table, txt_stage, item_numeric,
        item_word_embedding, item_sentence_emb, item_feat_idx,
        WTi, item_proj_b, item_num_W, item_num_b, x0, NI, KI, KIP, NU);

    // layer 0: x0 -> x1 (relu, bf16; overwrites the now-dead WTu/WTi)
    gnn_layer_kernel<<<NTOT / 64, 256, 0, stream>>>(
        x0, neighbors, VT0, W20, v_b, w_b, x1, 0);

    // re-prep layer-1 weights into dead x0 region
    prep_wt<<<dim3(1, 64), 256, 0, stream>>>(v_W + 64 * 64, VT1, 64, 64);
    prep_wt<<<dim3(1, 64), 256, 0, stream>>>(w_W + 128 * 64, W21, 128, 128);

    // layer 1 + fused normalize: x1 -> d_out (fp32, overwrites staging+weights)
    gnn_layer_kernel<<<NTOT / 64, 256, 0, stream>>>(
        x1, neighbors, VT1, W21, v_b + 64, w_b + 64, d_out, 1);
}